// Round 4
// baseline (855.143 us; speedup 1.0000x reference)
//
#include <hip/hip_runtime.h>
#include <cstdint>

#pragma clang fp contract(off)

#define TPB 256
typedef unsigned int uint32;
typedef unsigned long long u64;

constexpr int BB = 256;    // batch
constexpr int NN = 8732;   // boxes
constexpr int CC = 21;     // classes
constexpr int KK = 200;    // top-k
constexpr int CH = (NN + TPB - 1) / TPB;   // 35 contiguous elems per thread (index order)
constexpr uint32 KBIAS = 0x3C23D70Au;      // bits(0.01f); kk = bits(p)-KBIAS in [1, 0x35C28F6]

// ---------------- fast f64 exp (fast path only; guarded by interval check) ----------------
// |err| <= ~2 ulp for args in [-50, 10]. NOT bit-exact vs libm — every consumer must
// interval-guard and fall back to libm exp() when near an f32 rounding boundary.
__device__ __forceinline__ double fexp(double a) {
  const double L2E = 1.4426950408889634074;
  const double SHIFT = 6755399441055744.0;  // 1.5*2^52
  double t = __builtin_fma(a, L2E, SHIFT);
  int i = (int)__double_as_longlong(t);     // round-to-nearest integer n
  double n = t - SHIFT;
  double r = __builtin_fma(n, -6.93147180369123816490e-01, a);  // ln2_hi (trailing zeros)
  r = __builtin_fma(n, -1.90821492927058770002e-10, r);         // ln2_lo
  double p = 1.6059043836821614599e-10;     // 1/13! Horner
  p = __builtin_fma(p, r, 2.0876756987868098979e-9);
  p = __builtin_fma(p, r, 2.5052108385441718775e-8);
  p = __builtin_fma(p, r, 2.7557319223985890653e-7);
  p = __builtin_fma(p, r, 2.7557319223985890653e-6);
  p = __builtin_fma(p, r, 2.4801587301587301587e-5);
  p = __builtin_fma(p, r, 1.9841269841269841270e-4);
  p = __builtin_fma(p, r, 1.3888888888888888889e-3);
  p = __builtin_fma(p, r, 8.3333333333333333333e-3);
  p = __builtin_fma(p, r, 4.1666666666666666667e-2);
  p = __builtin_fma(p, r, 1.6666666666666666667e-1);
  p = __builtin_fma(p, r, 0.5);
  p = __builtin_fma(p, r, 1.0);
  p = __builtin_fma(p, r, 1.0);
  return p * __longlong_as_double((long long)(1023 + i) << 52);
}

// ---------------- shared memory ----------------
struct NmsS {
  alignas(16) float bx1[256];
  alignas(16) float by1[256];
  alignas(16) float bx2[256];
  alignas(16) float by2[256];
  alignas(16) float barea[256];
  alignas(16) float bscore[256];
  alignas(16) u64 mask[KK][4];
  u64 kept[4];
};
struct SelS {
  uint32 hist[512];              // 2 KB
  alignas(16) u64 cand[256];     // 2 KB
};
struct SmemT {
  union alignas(16) UU { SelS sel; NmsS nms; } u;   // 12.6 KB
  uint32 sc4[4];
  uint32 bc[2];
  uint32 slot;
};
static_assert(sizeof(SmemT) <= 13 * 1024, "LDS budget for 6+ blocks/CU");

__device__ __forceinline__ uint32 kk_of(float p) {
  return (p > 0.01f) ? (__float_as_uint(p) - KBIAS) : 0u;  // 0 = sentinel (-1.0 masked)
}

// suffix-scan 512 bins (2/thread), find pivot for `target`, zero hist, return totals
__device__ __forceinline__ void scan_find(SmemT& sm, uint32 target, int t, int lane, int wv,
                                          uint32& pivot, uint32& cntabove, uint32& total) {
  uint32 h0 = sm.u.sel.hist[2 * t], h1 = sm.u.sel.hist[2 * t + 1];
  uint32 part = h0 + h1;
  uint32 suf = part;
  for (int off = 1; off < 64; off <<= 1) {
    uint32 v = __shfl_down(suf, off, 64);
    if (lane + off < 64) suf += v;
  }
  if (lane == 0) sm.sc4[wv] = suf;
  __syncthreads();
  uint32 tot = sm.sc4[0] + sm.sc4[1] + sm.sc4[2] + sm.sc4[3];
  uint32 add = 0;
  for (int w = wv + 1; w < 4; ++w) add += sm.sc4[w];
  uint32 mine = suf + add, nxt = mine - part;
  if (mine >= target && nxt < target) {  // unique crossing thread (when target<=tot)
    uint32 acc = nxt + h1;
    if (acc >= target) { sm.bc[0] = 2u * t + 1u; sm.bc[1] = nxt; }
    else               { sm.bc[0] = 2u * t;      sm.bc[1] = acc; }
  }
  __syncthreads();
  sm.u.sel.hist[2 * t] = 0u;
  sm.u.sel.hist[2 * t + 1] = 0u;
  pivot = sm.bc[0];
  cntabove = sm.bc[1];
  total = tot;
  __syncthreads();  // hist zeroed & bc consumed before next pass's atomics
}

// ---------------- kernel 1: canonical double softmax, fexp fast path + exact fallback ----
template <int MODE>
__global__ __launch_bounds__(TPB) void prep_kernel(const float* __restrict__ conf,
                                                   float* __restrict__ probsT,
                                                   double2* __restrict__ ms) {
  const int n = blockIdx.x * TPB + threadIdx.x;
  const int b = blockIdx.y;
  if (n >= NN) return;
  const float* cp = conf + ((size_t)b * NN + n) * CC;
  float xs[CC];
#pragma unroll
  for (int j = 0; j < CC; ++j) xs[j] = cp[j];
  float mx = xs[0];
#pragma unroll
  for (int j = 1; j < CC; ++j) mx = fmaxf(mx, xs[j]);

  if (MODE == 0) {
    // fast path: fexp softmax; rigorous interval guard vs the libm spec value
    double es[CC];
    double S = 0.0;
#pragma unroll
    for (int j = 0; j < CC; ++j) {
      es[j] = fexp((double)xs[j] - (double)mx);
      S += es[j];
    }
    double Sinv = 1.0 / S;
    const double EBH = 1.0 + 3e-14, EBL = 1.0 - 3e-14;  // 4x margin over 7.5e-15 bound
    float p20[CC - 1];
    bool slow = false;
#pragma unroll
    for (int c2 = 1; c2 < CC; ++c2) {
      double ph = es[c2] * Sinv;
      if ((float)(ph * EBH) != (float)(ph * EBL)) slow = true;
      p20[c2 - 1] = (float)ph;
    }
    if (__builtin_expect(slow, 0)) {  // exact spec path (libm exp, sequential sum)
      double es2[CC];
      double S2 = 0.0;
      for (int j = 0; j < CC; ++j) {
        es2[j] = exp((double)xs[j] - (double)mx);
        S2 += es2[j];
      }
      double Si2 = 1.0 / S2;
      for (int c2 = 1; c2 < CC; ++c2) p20[c2 - 1] = (float)(es2[c2] * Si2);
    }
#pragma unroll
    for (int c2 = 1; c2 < CC; ++c2)
      probsT[((size_t)b * 20 + (c2 - 1)) * NN + n] = p20[c2 - 1];
  } else {
    // fallback workspace mode: pure libm spec values
    double S = 0.0;
#pragma unroll
    for (int j = 0; j < CC; ++j) S += exp((double)xs[j] - (double)mx);
    ms[(size_t)b * NN + n] = make_double2((double)mx, 1.0 / S);
  }
}

// per-n prob for fallback modes (libm exp only — bit-exact spec)
template <int MODE>
__device__ __forceinline__ float prob_one(const float* __restrict__ prow,
                                          const float* __restrict__ conf,
                                          const double2* __restrict__ ms,
                                          int b, int c, int n) {
  if (MODE == 0) {
    return prow[n];
  } else if (MODE == 1) {
    double2 mv = ms[(size_t)b * NN + n];
    float x = conf[((size_t)b * NN + n) * CC + c];
    return (float)(exp((double)x - mv.x) * mv.y);
  } else {
    const float* cp = conf + ((size_t)b * NN + n) * CC;
    float mx = cp[0];
    for (int j = 1; j < CC; ++j) mx = fmaxf(mx, cp[j]);
    double S = 0.0, ec = 0.0;
    for (int j = 0; j < CC; ++j) {
      double e = exp((double)cp[j] - (double)mx);
      S += e;
      if (j == c) ec = e;
    }
    return (float)(ec * (1.0 / S));
  }
}

// ---------------- kernel 2: per-(b,c) top-k + NMS + output ----------------
template <int MODE>
__global__ __launch_bounds__(TPB, 6) void nms_kernel(
    const float* __restrict__ probsT, const float* __restrict__ conf,
    const double2* __restrict__ ms, const float* __restrict__ loc,
    const float* __restrict__ dbox, float* __restrict__ out) {
  __shared__ SmemT sm;
  const int t = threadIdx.x;
  const int lane = t & 63;
  const int wv = t >> 6;
  const int tb = blockIdx.x;       // XCD-locality swizzle
  const int xcd = tb & 7;
  const int s0i = tb >> 3;
  const int bi = s0i / CC;
  const int c = s0i - bi * CC;
  const int b = bi * 8 + xcd;
  const size_t outbase = (size_t)(b * CC + c) * KK * 5;

  if (c == 0) {  // reference zeroes class 0
    for (int i = t; i < KK * 5; i += TPB) out[outbase + i] = 0.0f;
    return;
  }
  const float* prow = (MODE == 0) ? probsT + ((size_t)b * 20 + (c - 1)) * NN : nullptr;

  sm.u.sel.hist[t] = 0u;
  sm.u.sel.hist[t + 256] = 0u;
  if (t == 0) sm.slot = 0u;
  __syncthreads();

  // ---- pass 0 histogram: bins = kk>>17 (well-spread over ~200-430 bins) ----
  if (MODE == 0) {
    const float4* p4 = (const float4*)prow;   // NN = 4*2183 exactly
    for (int i = t; i < NN / 4; i += TPB) {
      float4 p = p4[i];
      uint32 k0 = kk_of(p.x), k1 = kk_of(p.y), k2 = kk_of(p.z), k3 = kk_of(p.w);
      if (k0) atomicAdd(&sm.u.sel.hist[k0 >> 17], 1u);
      if (k1) atomicAdd(&sm.u.sel.hist[k1 >> 17], 1u);
      if (k2) atomicAdd(&sm.u.sel.hist[k2 >> 17], 1u);
      if (k3) atomicAdd(&sm.u.sel.hist[k3 >> 17], 1u);
    }
  } else {
    for (int n = t; n < NN; n += TPB) {
      uint32 k = kk_of(prob_one<MODE>(prow, conf, ms, b, c, n));
      if (k) atomicAdd(&sm.u.sel.hist[k >> 17], 1u);
    }
  }
  __syncthreads();
  uint32 p0, cg0, total;
  scan_find(sm, (uint32)KK, t, lane, wv, p0, cg0, total);

  uint32 T, cnt_gt;
  if (total >= (uint32)KK) {
    // ---- pass 1: bins = (kk>>8)&0x1FF within prefix p0 ----
    uint32 tgt1 = (uint32)KK - cg0;
    if (MODE == 0) {
      const float4* p4 = (const float4*)prow;
      for (int i = t; i < NN / 4; i += TPB) {
        float4 p = p4[i];
        uint32 kk4[4] = {kk_of(p.x), kk_of(p.y), kk_of(p.z), kk_of(p.w)};
#pragma unroll
        for (int e = 0; e < 4; ++e) {
          uint32 k = kk4[e];
          if (k && (k >> 17) == p0) atomicAdd(&sm.u.sel.hist[(k >> 8) & 0x1FFu], 1u);
        }
      }
    } else {
      for (int n = t; n < NN; n += TPB) {
        uint32 k = kk_of(prob_one<MODE>(prow, conf, ms, b, c, n));
        if (k && (k >> 17) == p0) atomicAdd(&sm.u.sel.hist[(k >> 8) & 0x1FFu], 1u);
      }
    }
    __syncthreads();
    uint32 p1, cg1, tot1;
    scan_find(sm, tgt1, t, lane, wv, p1, cg1, tot1);

    // ---- pass 2: bins = kk&0xFF within prefix (p0<<9)|p1 ----
    const uint32 pref2 = (p0 << 9) | p1;
    uint32 tgt2 = tgt1 - cg1;
    if (MODE == 0) {
      const float4* p4 = (const float4*)prow;
      for (int i = t; i < NN / 4; i += TPB) {
        float4 p = p4[i];
        uint32 kk4[4] = {kk_of(p.x), kk_of(p.y), kk_of(p.z), kk_of(p.w)};
#pragma unroll
        for (int e = 0; e < 4; ++e) {
          uint32 k = kk4[e];
          if (k && (k >> 8) == pref2) atomicAdd(&sm.u.sel.hist[k & 0xFFu], 1u);
        }
      }
    } else {
      for (int n = t; n < NN; n += TPB) {
        uint32 k = kk_of(prob_one<MODE>(prow, conf, ms, b, c, n));
        if (k && (k >> 8) == pref2) atomicAdd(&sm.u.sel.hist[k & 0xFFu], 1u);
      }
    }
    __syncthreads();
    uint32 p2, cg2, tot2;
    scan_find(sm, tgt2, t, lane, wv, p2, cg2, tot2);

    T = (p0 << 17) | (p1 << 8) | p2;
    cnt_gt = cg0 + cg1 + cg2;
  } else {
    T = 0u;               // take all valid + lowest-index sentinels (ref: equal -1.0 ties)
    cnt_gt = total;
  }
  const uint32 m_need = (uint32)KK - cnt_gt;

  // ---- stable selection of exactly 200 candidates ----
  sm.u.sel.cand[t] = 0ull;  // padding sorts last
  __syncthreads();
  const int base = t * CH;
  const int endn = (base + CH < NN) ? (base + CH) : NN;
  uint32 cnteq = 0;
  for (int n = base; n < endn; ++n) {
    uint32 k = kk_of(prob_one<MODE>(prow, conf, ms, b, c, n));
    if (k > T) {
      uint32 s = atomicAdd(&sm.slot, 1u);
      sm.u.sel.cand[s] = ((u64)k << 32) | (uint32)(~(uint32)n);
    }
    cnteq += (k == T);
  }
  uint32 incl = cnteq;
  for (int off = 1; off < 64; off <<= 1) {
    uint32 v = __shfl_up(incl, off, 64);
    if (lane >= off) incl += v;
  }
  if (lane == 63) sm.sc4[wv] = incl;
  __syncthreads();
  uint32 add2 = 0;
  for (int w = 0; w < wv; ++w) add2 += sm.sc4[w];
  uint32 g = add2 + incl - cnteq;  // exclusive rank among equals, global index order
  if (cnteq && g < m_need) {
    for (int n = base; n < endn && g < m_need; ++n) {
      uint32 k = kk_of(prob_one<MODE>(prow, conf, ms, b, c, n));
      if (k == T) {
        sm.u.sel.cand[cnt_gt + g] = ((u64)T << 32) | (uint32)(~(uint32)n);
        ++g;
      }
    }
  }
  __syncthreads();

  // ---- bitonic sort 256 in registers (key desc, idx asc) ----
  u64 val = sm.u.sel.cand[t];
  for (int kk = 2; kk <= 256; kk <<= 1) {
    for (int j = kk >> 1; j > 0; j >>= 1) {
      u64 other;
      if (j >= 64) {
        __syncthreads();
        sm.u.sel.cand[t] = val;
        __syncthreads();
        other = sm.u.sel.cand[t ^ j];
      } else {
        other = __shfl_xor((unsigned long long)val, j, 64);
      }
      const bool takeMax = ((t & kk) == 0) == ((t & j) == 0);
      val = takeMax ? (val > other ? val : other) : (val < other ? val : other);
    }
  }
  __syncthreads();  // cand/hist alias nms arrays: drain before decode writes

  // ---- gather + decode (exact reference fp32 op order; libm exp) ----
  if (t < KK) {
    uint32 k32 = (uint32)(val >> 32);
    uint32 idx = ~((uint32)val);
    bool valid = k32 != 0u;
    float score = valid ? __uint_as_float(k32 + KBIAS) : -1.0f;
    const float4 lc = ((const float4*)loc)[(size_t)b * NN + idx];
    const float4 db = ((const float4*)dbox)[idx];
    float cx = db.x + (lc.x * 0.1f) * db.z;
    float cy = db.y + (lc.y * 0.1f) * db.w;
    float w_ = db.z * (float)exp((double)(lc.z * 0.2f));
    float h_ = db.w * (float)exp((double)(lc.w * 0.2f));
    float x1 = cx - w_ * 0.5f;
    float y1 = cy - h_ * 0.5f;
    float x2 = x1 + w_;
    float y2 = y1 + h_;
    sm.u.nms.bx1[t] = x1;
    sm.u.nms.by1[t] = y1;
    sm.u.nms.bx2[t] = x2;
    sm.u.nms.by2[t] = y2;
    sm.u.nms.barea[t] = (x2 - x1) * (y2 - y1);
    sm.u.nms.bscore[t] = score;
  } else {
    sm.u.nms.bscore[t] = -1.0f;
  }
  __syncthreads();

  // ---- IoU mask rows: sign-correct exact f64 compare, div-free ----
  // uni>0: fl(inter/uni)>0.45f <=> inter > mid(0.45f,next)*uni (25b x 24b product exact)
  // uni<0: quotient <= 0 -> false.  uni==+0: inter>0 -> +inf -> true; inter==0 -> NaN -> false.
  if (t < KK) {
    const double MD = 0x1.CCCCCDp-2;
    const float xi1 = sm.u.nms.bx1[t], yi1 = sm.u.nms.by1[t];
    const float xi2 = sm.u.nms.bx2[t], yi2 = sm.u.nms.by2[t];
    const float ai = sm.u.nms.barea[t];
#pragma unroll
    for (int wq = 0; wq < 4; ++wq) {
      const int jbeg = wq * 64;
      const int jend = (jbeg + 64 < KK) ? (jbeg + 64) : KK;
      u64 w = 0;
      for (int j0 = jbeg; j0 < jend; j0 += 4) {
        const float4 q1 = *(const float4*)&sm.u.nms.bx1[j0];
        const float4 q2 = *(const float4*)&sm.u.nms.by1[j0];
        const float4 q3 = *(const float4*)&sm.u.nms.bx2[j0];
        const float4 q4 = *(const float4*)&sm.u.nms.by2[j0];
        const float4 qa = *(const float4*)&sm.u.nms.barea[j0];
        const float a1[4] = {q1.x, q1.y, q1.z, q1.w};
        const float a2[4] = {q2.x, q2.y, q2.z, q2.w};
        const float a3[4] = {q3.x, q3.y, q3.z, q3.w};
        const float a4[4] = {q4.x, q4.y, q4.z, q4.w};
        const float aa[4] = {qa.x, qa.y, qa.z, qa.w};
#pragma unroll
        for (int e = 0; e < 4; ++e) {
          const int j = j0 + e;
          float xx1 = fmaxf(a1[e], xi1);
          float yy1 = fmaxf(a2[e], yi1);
          float xx2 = fmaxf(a3[e], xi2);
          float yy2 = fmaxf(a4[e], yi2);
          float inter = (xx2 - xx1) * (yy2 - yy1);   // >= 0 (all-max corners, ref quirk)
          float uni = (aa[e] - inter) + ai;          // exact ref op order; may be <= 0
          bool sup = (uni > 0.0f) ? ((double)inter > MD * (double)uni)
                                  : (uni == 0.0f && inter > 0.0f);
          if (sup && j != t) w |= 1ull << (j & 63);
        }
      }
      sm.u.nms.mask[t][wq] = w;
    }
  }
  __syncthreads();

  // ---- greedy walk on wave 0 only ----
  if (wv == 0) {
    u64 s0 = __ballot(!(sm.u.nms.bscore[lane] > 0.01f));
    u64 s1 = __ballot(!(sm.u.nms.bscore[64 + lane] > 0.01f));
    u64 s2 = __ballot(!(sm.u.nms.bscore[128 + lane] > 0.01f));
    u64 s3 = __ballot(!(sm.u.nms.bscore[192 + lane] > 0.01f)) | ~0xFFull;
    u64 k0 = 0, k1 = 0, k2 = 0, k3 = 0;
    const u64(*M)[4] = sm.u.nms.mask;
    u64 n0 = M[0][0], n1 = M[0][1], n2 = M[0][2], n3 = M[0][3];
    int i = 0;
#define WALK_BLOCK(SW, KW, CNT)                                          \
  for (int ii = 0; ii < (CNT); ++ii, ++i) {                              \
    u64 c0 = n0, c1 = n1, c2 = n2, c3 = n3;                              \
    if (i + 1 < KK) {                                                    \
      n0 = M[i + 1][0]; n1 = M[i + 1][1];                                \
      n2 = M[i + 1][2]; n3 = M[i + 1][3];                                \
    }                                                                    \
    u64 bm = 1ull << ii;                                                 \
    if (!((SW) & bm)) {                                                  \
      (KW) |= bm;                                                        \
      s0 |= c0; s1 |= c1; s2 |= c2; s3 |= c3;                            \
    }                                                                    \
  }
    WALK_BLOCK(s0, k0, 64)
    WALK_BLOCK(s1, k1, 64)
    WALK_BLOCK(s2, k2, 64)
    WALK_BLOCK(s3, k3, 8)
#undef WALK_BLOCK
    if (lane == 0) {
      sm.u.nms.kept[0] = k0; sm.u.nms.kept[1] = k1;
      sm.u.nms.kept[2] = k2; sm.u.nms.kept[3] = k3;
    }
  }
  __syncthreads();

  // ---- compacted output ----
  if (t < KK) {
    const u64 K0 = sm.u.nms.kept[0], K1 = sm.u.nms.kept[1];
    const u64 K2 = sm.u.nms.kept[2], K3 = sm.u.nms.kept[3];
    const int w = t >> 6;
    const int bit = t & 63;
    u64 kw = (w == 0) ? K0 : (w == 1) ? K1 : (w == 2) ? K2 : K3;
    bool kp = (kw >> bit) & 1ull;
    int nk = __popcll(K0) + __popcll(K1) + __popcll(K2) + __popcll(K3);
    if (kp) {
      u64 lowm = (bit == 0) ? 0ull : (~0ull >> (64 - bit));
      int d = __popcll(kw & lowm);
      if (w > 0) d += __popcll(K0);
      if (w > 1) d += __popcll(K1);
      if (w > 2) d += __popcll(K2);
      float* o = out + outbase + (size_t)d * 5;
      o[0] = sm.u.nms.bscore[t];
      o[1] = sm.u.nms.bx1[t];
      o[2] = sm.u.nms.by1[t];
      o[3] = sm.u.nms.bx2[t];
      o[4] = sm.u.nms.by2[t];
    }
    if (t >= nk) {
      float* o = out + outbase + (size_t)t * 5;
      o[0] = 0.f; o[1] = 0.f; o[2] = 0.f; o[3] = 0.f; o[4] = 0.f;
    }
  }
}

// ---------------- launch ----------------
extern "C" void kernel_launch(void* const* d_in, const int* in_sizes, int n_in,
                              void* d_out, int out_size, void* d_ws, size_t ws_size,
                              hipStream_t stream) {
  (void)in_sizes; (void)n_in; (void)out_size;
  const float* loc = (const float*)d_in[0];
  const float* conf = (const float*)d_in[1];
  const float* dbox = (const float*)d_in[2];
  float* out = (float*)d_out;

  const size_t needA = (size_t)BB * 20 * NN * sizeof(float);  // 178.8 MB transposed probs
  const size_t needB = (size_t)BB * NN * sizeof(double2);     // 35.8 MB {max, 1/S}
  dim3 blk(TPB);
  dim3 g1((NN + TPB - 1) / TPB, BB);
  const int g2 = BB * CC;

  if (ws_size >= needA) {
    float* probsT = (float*)d_ws;
    prep_kernel<0><<<g1, blk, 0, stream>>>(conf, probsT, nullptr);
    nms_kernel<0><<<g2, blk, 0, stream>>>(probsT, conf, nullptr, loc, dbox, out);
  } else if (ws_size >= needB) {
    double2* msp = (double2*)d_ws;
    prep_kernel<1><<<g1, blk, 0, stream>>>(conf, nullptr, msp);
    nms_kernel<1><<<g2, blk, 0, stream>>>(nullptr, conf, msp, loc, dbox, out);
  } else {
    nms_kernel<2><<<g2, blk, 0, stream>>>(nullptr, conf, nullptr, loc, dbox, out);
  }
}

// Round 5
// 547.971 us; speedup vs baseline: 1.5606x; 1.5606x over previous
//
#include <hip/hip_runtime.h>
#include <cstdint>

#pragma clang fp contract(off)

#define TPB 256
typedef unsigned int uint32;
typedef unsigned short u16;
typedef unsigned long long u64;

constexpr int BB = 256;    // batch
constexpr int NN = 8732;   // boxes
constexpr int CC = 21;     // classes
constexpr int KK = 200;    // top-k
constexpr int CH = (NN + TPB - 1) / TPB;   // 35 contiguous elems per thread (index order)
constexpr uint32 KBIAS = 0x3C23D70Au;      // bits(0.01f); kk = bits(p)-KBIAS in [1, 0x35C28F6]

// ---------------- fast f64 exp (fast path only; guarded by interval check) ----------------
__device__ __forceinline__ double fexp(double a) {
  const double L2E = 1.4426950408889634074;
  const double SHIFT = 6755399441055744.0;  // 1.5*2^52
  double t = __builtin_fma(a, L2E, SHIFT);
  int i = (int)__double_as_longlong(t);
  double n = t - SHIFT;
  double r = __builtin_fma(n, -6.93147180369123816490e-01, a);
  r = __builtin_fma(n, -1.90821492927058770002e-10, r);
  double p = 1.6059043836821614599e-10;
  p = __builtin_fma(p, r, 2.0876756987868098979e-9);
  p = __builtin_fma(p, r, 2.5052108385441718775e-8);
  p = __builtin_fma(p, r, 2.7557319223985890653e-7);
  p = __builtin_fma(p, r, 2.7557319223985890653e-6);
  p = __builtin_fma(p, r, 2.4801587301587301587e-5);
  p = __builtin_fma(p, r, 1.9841269841269841270e-4);
  p = __builtin_fma(p, r, 1.3888888888888888889e-3);
  p = __builtin_fma(p, r, 8.3333333333333333333e-3);
  p = __builtin_fma(p, r, 4.1666666666666666667e-2);
  p = __builtin_fma(p, r, 1.6666666666666666667e-1);
  p = __builtin_fma(p, r, 0.5);
  p = __builtin_fma(p, r, 1.0);
  p = __builtin_fma(p, r, 1.0);
  return p * __longlong_as_double((long long)(1023 + i) << 52);
}

// ---------------- shared memory ----------------
struct NmsS {
  alignas(16) float bx1[256];
  alignas(16) float by1[256];
  alignas(16) float bx2[256];
  alignas(16) float by2[256];
  alignas(16) float barea[256];
  alignas(16) float bscore[256];
  alignas(16) u64 mask[KK][4];
  u64 kept[4];
};
struct SmemT {
  union alignas(16) UU {
    u16 s16[NN];   // 17464 B (select phase; 16-bit bucket keys)
    NmsS nms;      // 12576 B (NMS phase)
  } u;
  uint32 hist[512];
  alignas(16) u64 cand[256];
  uint32 sc4[4];
  uint32 bc[3];
  uint32 slot;
};
static_assert(sizeof(SmemT) <= 22 * 1024, "LDS budget for 7 blocks/CU");

__device__ __forceinline__ uint32 kk_of(float p) {
  return (p > 0.01f) ? (__float_as_uint(p) - KBIAS) : 0u;  // 0 = sentinel (-1.0 masked)
}

// suffix-scan 512 bins (2/thread), find pivot bin for `target`; outputs pivot,
// count-strictly-above, pivot-bin count, total; zeroes hist for the next pass.
__device__ __forceinline__ void scan_find(SmemT& sm, uint32 target, int t, int lane, int wv,
                                          uint32& pivot, uint32& cntabove, uint32& pivcnt,
                                          uint32& total) {
  uint32 h0 = sm.hist[2 * t], h1 = sm.hist[2 * t + 1];
  uint32 part = h0 + h1;
  uint32 suf = part;
  for (int off = 1; off < 64; off <<= 1) {
    uint32 v = __shfl_down(suf, off, 64);
    if (lane + off < 64) suf += v;
  }
  if (lane == 0) sm.sc4[wv] = suf;
  __syncthreads();
  uint32 tot = sm.sc4[0] + sm.sc4[1] + sm.sc4[2] + sm.sc4[3];
  uint32 add = 0;
  for (int w = wv + 1; w < 4; ++w) add += sm.sc4[w];
  uint32 mine = suf + add, nxt = mine - part;
  if (mine >= target && nxt < target) {  // unique crossing thread (when target<=tot)
    uint32 acc = nxt + h1;
    if (acc >= target) { sm.bc[0] = 2u * t + 1u; sm.bc[1] = nxt; sm.bc[2] = h1; }
    else               { sm.bc[0] = 2u * t;      sm.bc[1] = acc; sm.bc[2] = h0; }
  }
  __syncthreads();
  sm.hist[2 * t] = 0u;
  sm.hist[2 * t + 1] = 0u;
  pivot = sm.bc[0];
  cntabove = sm.bc[1];
  pivcnt = sm.bc[2];
  total = tot;
  __syncthreads();
}

// ---------------- kernel 1: canonical f64 softmax, two-pass register-light ----------------
// Values identical to the r4-validated pipeline: fexp fast path + interval guard +
// libm-exact fallback. xs stay in LDS tile (stride-21 reads: 2-way bank alias = free).
template <int MODE>
__global__ __launch_bounds__(TPB, 6) void prep_kernel(const float* __restrict__ conf,
                                                      float* __restrict__ probsT,
                                                      double2* __restrict__ ms) {
  __shared__ float tile[TPB * CC];  // 21504 B
  const int blk = blockIdx.x;
  const int b = blockIdx.y;
  const int n0 = blk * TPB;
  const int cnt = (NN - n0 < TPB) ? (NN - n0) : TPB;
  const size_t base = ((size_t)b * NN + n0) * CC;
  if (cnt == TPB) {
    const float4* s4 = (const float4*)(conf + base);  // 16B-aligned (NN%4==0, n0%4==0)
    float4* t4 = (float4*)tile;
    for (int i = threadIdx.x; i < (TPB * CC) / 4; i += TPB) t4[i] = s4[i];
  } else {
    for (int i = threadIdx.x; i < cnt * CC; i += TPB) tile[i] = conf[base + i];
  }
  __syncthreads();
  if (threadIdx.x >= cnt) return;
  const int n = n0 + threadIdx.x;
  const float* cp = tile + threadIdx.x * CC;
  float mx = cp[0];
#pragma unroll
  for (int j = 1; j < CC; ++j) mx = fmaxf(mx, cp[j]);
  const double mxd = (double)mx;

  if (MODE == 0) {
    double S = 0.0;
#pragma unroll
    for (int j = 0; j < CC; ++j) S += fexp((double)cp[j] - mxd);
    const double Sinv = 1.0 / S;
    const double EBH = 1.0 + 3e-14, EBL = 1.0 - 3e-14;
    bool slow = false;
    float* op = probsT + (size_t)b * 20 * NN + n;
#pragma unroll
    for (int c2 = 1; c2 < CC; ++c2) {
      double ph = fexp((double)cp[c2] - mxd) * Sinv;  // same value as r4's es[c2]*Sinv
      if ((float)(ph * EBH) != (float)(ph * EBL)) slow = true;
      op[(size_t)(c2 - 1) * NN] = (float)ph;
    }
    if (__builtin_expect(slow, 0)) {  // exact spec path (libm exp, sequential sum)
      double es2[CC];
      double S2 = 0.0;
      for (int j = 0; j < CC; ++j) {
        es2[j] = exp((double)cp[j] - mxd);
        S2 += es2[j];
      }
      double Si2 = 1.0 / S2;
      for (int c2 = 1; c2 < CC; ++c2) op[(size_t)(c2 - 1) * NN] = (float)(es2[c2] * Si2);
    }
  } else {
    double S = 0.0;
#pragma unroll
    for (int j = 0; j < CC; ++j) S += exp((double)cp[j] - mxd);
    ms[(size_t)b * NN + n] = make_double2(mxd, 1.0 / S);
  }
}

// per-n prob (MODE 0: exact f32 from probsT; MODE 1/2: libm-exact recompute)
template <int MODE>
__device__ __forceinline__ float prob_one(const float* __restrict__ prow,
                                          const float* __restrict__ conf,
                                          const double2* __restrict__ ms,
                                          int b, int c, int n) {
  if (MODE == 0) {
    return prow[n];
  } else if (MODE == 1) {
    double2 mv = ms[(size_t)b * NN + n];
    float x = conf[((size_t)b * NN + n) * CC + c];
    return (float)(exp((double)x - mv.x) * mv.y);
  } else {
    const float* cp = conf + ((size_t)b * NN + n) * CC;
    float mx = cp[0];
    for (int j = 1; j < CC; ++j) mx = fmaxf(mx, cp[j]);
    double S = 0.0, ec = 0.0;
    for (int j = 0; j < CC; ++j) {
      double e = exp((double)cp[j] - (double)mx);
      S += e;
      if (j == c) ec = e;
    }
    return (float)(ec * (1.0 / S));
  }
}

// ---------------- kernel 2: per-(b,c) top-k + NMS + output ----------------
template <int MODE>
__global__ __launch_bounds__(TPB, 7) void nms_kernel(
    const float* __restrict__ probsT, const float* __restrict__ conf,
    const double2* __restrict__ ms, const float* __restrict__ loc,
    const float* __restrict__ dbox, float* __restrict__ out) {
  __shared__ SmemT sm;
  const int t = threadIdx.x;
  const int lane = t & 63;
  const int wv = t >> 6;
  const int tb = blockIdx.x;       // XCD-locality swizzle
  const int xcd = tb & 7;
  const int s0i = tb >> 3;
  const int bi = s0i / CC;
  const int c = s0i - bi * CC;
  const int b = bi * 8 + xcd;
  const size_t outbase = (size_t)(b * CC + c) * KK * 5;

  if (c == 0) {  // reference zeroes class 0
    for (int i = t; i < KK * 5; i += TPB) out[outbase + i] = 0.0f;
    return;
  }
  const float* prow = (MODE == 0) ? probsT + ((size_t)b * 20 + (c - 1)) * NN : nullptr;

  sm.hist[t] = 0u;
  sm.hist[t + 256] = 0u;
  if (t == 0) sm.slot = 0u;
  __syncthreads();

  // ---- build 16-bit bucket keys in LDS (ONE global row read) + pass-0 hist ----
  // s16 = (kk>>10)+1 for valid, 0 for sentinel; pass-0 bins = s16>>8 (max 0xD7, spread)
  if (MODE == 0) {
    const float4* p4 = (const float4*)prow;   // NN = 4*2183
    for (int i = t; i < NN / 4; i += TPB) {
      float4 p = p4[i];
      uint32 k0 = kk_of(p.x), k1 = kk_of(p.y), k2 = kk_of(p.z), k3 = kk_of(p.w);
      uint32 s0 = k0 ? (k0 >> 10) + 1u : 0u;
      uint32 s1 = k1 ? (k1 >> 10) + 1u : 0u;
      uint32 s2 = k2 ? (k2 >> 10) + 1u : 0u;
      uint32 s3 = k3 ? (k3 >> 10) + 1u : 0u;
      ((u64*)sm.u.s16)[i] = (u64)s0 | ((u64)s1 << 16) | ((u64)s2 << 32) | ((u64)s3 << 48);
      if (s0) atomicAdd(&sm.hist[s0 >> 8], 1u);
      if (s1) atomicAdd(&sm.hist[s1 >> 8], 1u);
      if (s2) atomicAdd(&sm.hist[s2 >> 8], 1u);
      if (s3) atomicAdd(&sm.hist[s3 >> 8], 1u);
    }
  } else {
    for (int n = t; n < NN; n += TPB) {
      uint32 k = kk_of(prob_one<MODE>(prow, conf, ms, b, c, n));
      uint32 s = k ? (k >> 10) + 1u : 0u;
      sm.u.s16[n] = (u16)s;
      if (s) atomicAdd(&sm.hist[s >> 8], 1u);
    }
  }
  __syncthreads();
  uint32 P0, cg0, pc0, total;
  scan_find(sm, (uint32)KK, t, lane, wv, P0, cg0, pc0, total);

  const bool few = total < (uint32)KK;
  uint32 P16, cgA = 0, eqc = 0, ncand;
  if (!few) {
    // ---- pass 1: bins = s16 & 0xFF within high-byte P0 (LDS scan, no global) ----
    for (int i = t; i < NN / 2; i += TPB) {
      uint32 w = ((const uint32*)sm.u.s16)[i];
      uint32 a = w & 0xFFFFu, bq = w >> 16;
      if ((a >> 8) == P0) atomicAdd(&sm.hist[a & 0xFFu], 1u);
      if ((bq >> 8) == P0) atomicAdd(&sm.hist[bq & 0xFFu], 1u);
    }
    __syncthreads();
    uint32 P1, cg1, pc1, tot1;
    scan_find(sm, (uint32)KK - cg0, t, lane, wv, P1, cg1, pc1, tot1);
    P16 = (P0 << 8) | P1;
    cgA = cg0 + cg1;
    eqc = pc1;
    ncand = cgA + eqc;   // count with s16 >= P16 (superset of top-200)
  } else {
    P16 = 1u;            // all valid boxes are candidates
    ncand = total;
  }

  u64 val = 0;
  if (ncand <= 256u) {
    // ---- fast path: collect candidate indices, gather exact probs, sort exactly ----
    sm.cand[t] = 0ull;
    __syncthreads();
    for (int i = t; i < NN / 2; i += TPB) {
      uint32 w = ((const uint32*)sm.u.s16)[i];
      uint32 a = w & 0xFFFFu, bq = w >> 16;
      if (a >= P16) { uint32 s = atomicAdd(&sm.slot, 1u); sm.cand[s] = (u64)(2 * i); }
      if (bq >= P16) { uint32 s = atomicAdd(&sm.slot, 1u); sm.cand[s] = (u64)(2 * i + 1); }
    }
    __syncthreads();
    if (few) {
      // pad with the lowest-index (200-total) masked boxes (equal -1.0 ties by index)
      const int base = t * CH;
      const int endn = (base + CH < NN) ? (base + CH) : NN;
      uint32 cz = 0;
      for (int n = base; n < endn; ++n) cz += (sm.u.s16[n] == 0);
      uint32 incl = cz;
      for (int off = 1; off < 64; off <<= 1) {
        uint32 v = __shfl_up(incl, off, 64);
        if (lane >= off) incl += v;
      }
      if (lane == 63) sm.sc4[wv] = incl;
      __syncthreads();
      uint32 add = 0;
      for (int w2 = 0; w2 < wv; ++w2) add += sm.sc4[w2];
      uint32 g = add + incl - cz;
      const uint32 npad = (uint32)KK - ncand;
      if (cz && g < npad) {
        for (int n = base; n < endn && g < npad; ++n)
          if (sm.u.s16[n] == 0) { sm.cand[ncand + g] = (u64)n; ++g; }
      }
      __syncthreads();
    }
    const uint32 ntot = few ? (uint32)KK : ncand;   // >= 200 always
    if (t < (int)ntot) {
      uint32 idx = (uint32)sm.cand[t];
      uint32 k = (t < (int)ncand) ? kk_of(prob_one<MODE>(prow, conf, ms, b, c, (int)idx)) : 0u;
      val = ((u64)k << 32) | (uint32)(~idx);
    }
  } else {
    // ---- rare exact fallback: refine low 10 bits of kk within bucket P16-1 ----
    const uint32 BK = P16 - 1u;
    const uint32 tgt = (uint32)KK - cgA;
    for (int n = t; n < NN; n += TPB) {
      uint32 k = kk_of(prob_one<MODE>(prow, conf, ms, b, c, n));
      if (k && (k >> 10) == BK) atomicAdd(&sm.hist[(k >> 5) & 31u], 1u);
    }
    __syncthreads();
    uint32 q0, d0, px, tx;
    scan_find(sm, tgt, t, lane, wv, q0, d0, px, tx);
    for (int n = t; n < NN; n += TPB) {
      uint32 k = kk_of(prob_one<MODE>(prow, conf, ms, b, c, n));
      if (k && (k >> 5) == ((BK << 5) | q0)) atomicAdd(&sm.hist[k & 31u], 1u);
    }
    __syncthreads();
    uint32 q1, d1, py, ty;
    scan_find(sm, tgt - d0, t, lane, wv, q1, d1, py, ty);
    const uint32 T = (BK << 10) | (q0 << 5) | q1;
    const uint32 cnt_gt = cgA + d0 + d1;
    const uint32 m_need = (uint32)KK - cnt_gt;
    sm.cand[t] = 0ull;
    if (t == 0) sm.slot = 0u;
    __syncthreads();
    const int base = t * CH;
    const int endn = (base + CH < NN) ? (base + CH) : NN;
    uint32 cnteq = 0;
    for (int n = base; n < endn; ++n) {
      uint32 k = kk_of(prob_one<MODE>(prow, conf, ms, b, c, n));
      if (k > T) {
        uint32 s = atomicAdd(&sm.slot, 1u);
        sm.cand[s] = ((u64)k << 32) | (uint32)(~(uint32)n);
      }
      cnteq += (k == T);
    }
    uint32 incl = cnteq;
    for (int off = 1; off < 64; off <<= 1) {
      uint32 v = __shfl_up(incl, off, 64);
      if (lane >= off) incl += v;
    }
    if (lane == 63) sm.sc4[wv] = incl;
    __syncthreads();
    uint32 add = 0;
    for (int w2 = 0; w2 < wv; ++w2) add += sm.sc4[w2];
    uint32 g = add + incl - cnteq;
    if (cnteq && g < m_need) {
      for (int n = base; n < endn && g < m_need; ++n) {
        uint32 k = kk_of(prob_one<MODE>(prow, conf, ms, b, c, n));
        if (k == T) {
          sm.cand[cnt_gt + g] = ((u64)T << 32) | (uint32)(~(uint32)n);
          ++g;
        }
      }
    }
    __syncthreads();
    val = sm.cand[t];
  }

  // ---- bitonic sort 256 in registers (key desc, idx asc) ----
  for (int kk = 2; kk <= 256; kk <<= 1) {
    for (int j = kk >> 1; j > 0; j >>= 1) {
      u64 other;
      if (j >= 64) {
        __syncthreads();
        sm.cand[t] = val;
        __syncthreads();
        other = sm.cand[t ^ j];
      } else {
        other = __shfl_xor((unsigned long long)val, j, 64);
      }
      const bool takeMax = ((t & kk) == 0) == ((t & j) == 0);
      val = takeMax ? (val > other ? val : other) : (val < other ? val : other);
    }
  }
  __syncthreads();  // s16/nms union: drain last select-phase reads before decode writes

  // ---- gather + decode (exact reference fp32 op order; libm exp) ----
  if (t < KK) {
    uint32 k32 = (uint32)(val >> 32);
    uint32 idx = ~((uint32)val);
    bool valid = k32 != 0u;
    float score = valid ? __uint_as_float(k32 + KBIAS) : -1.0f;
    const float4 lc = ((const float4*)loc)[(size_t)b * NN + idx];
    const float4 db = ((const float4*)dbox)[idx];
    float cx = db.x + (lc.x * 0.1f) * db.z;
    float cy = db.y + (lc.y * 0.1f) * db.w;
    float w_ = db.z * (float)exp((double)(lc.z * 0.2f));
    float h_ = db.w * (float)exp((double)(lc.w * 0.2f));
    float x1 = cx - w_ * 0.5f;
    float y1 = cy - h_ * 0.5f;
    float x2 = x1 + w_;
    float y2 = y1 + h_;
    sm.u.nms.bx1[t] = x1;
    sm.u.nms.by1[t] = y1;
    sm.u.nms.bx2[t] = x2;
    sm.u.nms.by2[t] = y2;
    sm.u.nms.barea[t] = (x2 - x1) * (y2 - y1);
    sm.u.nms.bscore[t] = score;
  } else {
    sm.u.nms.bscore[t] = -1.0f;
  }
  __syncthreads();

  // ---- IoU mask rows: sign-correct exact f64 compare, div-free (r4-validated) ----
  if (t < KK) {
    const double MD = 0x1.CCCCCDp-2;
    const float xi1 = sm.u.nms.bx1[t], yi1 = sm.u.nms.by1[t];
    const float xi2 = sm.u.nms.bx2[t], yi2 = sm.u.nms.by2[t];
    const float ai = sm.u.nms.barea[t];
#pragma unroll
    for (int wq = 0; wq < 4; ++wq) {
      const int jbeg = wq * 64;
      const int jend = (jbeg + 64 < KK) ? (jbeg + 64) : KK;
      u64 w = 0;
      for (int j0 = jbeg; j0 < jend; j0 += 4) {
        const float4 q1 = *(const float4*)&sm.u.nms.bx1[j0];
        const float4 q2 = *(const float4*)&sm.u.nms.by1[j0];
        const float4 q3 = *(const float4*)&sm.u.nms.bx2[j0];
        const float4 q4 = *(const float4*)&sm.u.nms.by2[j0];
        const float4 qa = *(const float4*)&sm.u.nms.barea[j0];
        const float a1[4] = {q1.x, q1.y, q1.z, q1.w};
        const float a2[4] = {q2.x, q2.y, q2.z, q2.w};
        const float a3[4] = {q3.x, q3.y, q3.z, q3.w};
        const float a4[4] = {q4.x, q4.y, q4.z, q4.w};
        const float aa[4] = {qa.x, qa.y, qa.z, qa.w};
#pragma unroll
        for (int e = 0; e < 4; ++e) {
          const int j = j0 + e;
          float xx1 = fmaxf(a1[e], xi1);
          float yy1 = fmaxf(a2[e], yi1);
          float xx2 = fmaxf(a3[e], xi2);
          float yy2 = fmaxf(a4[e], yi2);
          float inter = (xx2 - xx1) * (yy2 - yy1);   // >= 0 (all-max corners, ref quirk)
          float uni = (aa[e] - inter) + ai;          // exact ref op order; may be <= 0
          bool sup = (uni > 0.0f) ? ((double)inter > MD * (double)uni)
                                  : (uni == 0.0f && inter > 0.0f);
          if (sup && j != t) w |= 1ull << (j & 63);
        }
      }
      sm.u.nms.mask[t][wq] = w;
    }
  }
  __syncthreads();

  // ---- greedy walk on wave 0 only ----
  if (wv == 0) {
    u64 s0 = __ballot(!(sm.u.nms.bscore[lane] > 0.01f));
    u64 s1 = __ballot(!(sm.u.nms.bscore[64 + lane] > 0.01f));
    u64 s2 = __ballot(!(sm.u.nms.bscore[128 + lane] > 0.01f));
    u64 s3 = __ballot(!(sm.u.nms.bscore[192 + lane] > 0.01f)) | ~0xFFull;
    u64 k0 = 0, k1 = 0, k2 = 0, k3 = 0;
    const u64(*M)[4] = sm.u.nms.mask;
    u64 n0 = M[0][0], n1 = M[0][1], n2 = M[0][2], n3 = M[0][3];
    int i = 0;
#define WALK_BLOCK(SW, KW, CNT)                                          \
  for (int ii = 0; ii < (CNT); ++ii, ++i) {                              \
    u64 c0 = n0, c1 = n1, c2 = n2, c3 = n3;                              \
    if (i + 1 < KK) {                                                    \
      n0 = M[i + 1][0]; n1 = M[i + 1][1];                                \
      n2 = M[i + 1][2]; n3 = M[i + 1][3];                                \
    }                                                                    \
    u64 bm = 1ull << ii;                                                 \
    if (!((SW) & bm)) {                                                  \
      (KW) |= bm;                                                        \
      s0 |= c0; s1 |= c1; s2 |= c2; s3 |= c3;                            \
    }                                                                    \
  }
    WALK_BLOCK(s0, k0, 64)
    WALK_BLOCK(s1, k1, 64)
    WALK_BLOCK(s2, k2, 64)
    WALK_BLOCK(s3, k3, 8)
#undef WALK_BLOCK
    if (lane == 0) {
      sm.u.nms.kept[0] = k0; sm.u.nms.kept[1] = k1;
      sm.u.nms.kept[2] = k2; sm.u.nms.kept[3] = k3;
    }
  }
  __syncthreads();

  // ---- compacted output ----
  if (t < KK) {
    const u64 K0 = sm.u.nms.kept[0], K1 = sm.u.nms.kept[1];
    const u64 K2 = sm.u.nms.kept[2], K3 = sm.u.nms.kept[3];
    const int w = t >> 6;
    const int bit = t & 63;
    u64 kw = (w == 0) ? K0 : (w == 1) ? K1 : (w == 2) ? K2 : K3;
    bool kp = (kw >> bit) & 1ull;
    int nk = __popcll(K0) + __popcll(K1) + __popcll(K2) + __popcll(K3);
    if (kp) {
      u64 lowm = (bit == 0) ? 0ull : (~0ull >> (64 - bit));
      int d = __popcll(kw & lowm);
      if (w > 0) d += __popcll(K0);
      if (w > 1) d += __popcll(K1);
      if (w > 2) d += __popcll(K2);
      float* o = out + outbase + (size_t)d * 5;
      o[0] = sm.u.nms.bscore[t];
      o[1] = sm.u.nms.bx1[t];
      o[2] = sm.u.nms.by1[t];
      o[3] = sm.u.nms.bx2[t];
      o[4] = sm.u.nms.by2[t];
    }
    if (t >= nk) {
      float* o = out + outbase + (size_t)t * 5;
      o[0] = 0.f; o[1] = 0.f; o[2] = 0.f; o[3] = 0.f; o[4] = 0.f;
    }
  }
}

// ---------------- launch ----------------
extern "C" void kernel_launch(void* const* d_in, const int* in_sizes, int n_in,
                              void* d_out, int out_size, void* d_ws, size_t ws_size,
                              hipStream_t stream) {
  (void)in_sizes; (void)n_in; (void)out_size;
  const float* loc = (const float*)d_in[0];
  const float* conf = (const float*)d_in[1];
  const float* dbox = (const float*)d_in[2];
  float* out = (float*)d_out;

  const size_t needA = (size_t)BB * 20 * NN * sizeof(float);  // 178.8 MB transposed probs
  const size_t needB = (size_t)BB * NN * sizeof(double2);     // 35.8 MB {max, 1/S}
  dim3 blk(TPB);
  dim3 g1((NN + TPB - 1) / TPB, BB);
  const int g2 = BB * CC;

  if (ws_size >= needA) {
    float* probsT = (float*)d_ws;
    prep_kernel<0><<<g1, blk, 0, stream>>>(conf, probsT, nullptr);
    nms_kernel<0><<<g2, blk, 0, stream>>>(probsT, conf, nullptr, loc, dbox, out);
  } else if (ws_size >= needB) {
    double2* msp = (double2*)d_ws;
    prep_kernel<1><<<g1, blk, 0, stream>>>(conf, nullptr, msp);
    nms_kernel<1><<<g2, blk, 0, stream>>>(nullptr, conf, msp, loc, dbox, out);
  } else {
    nms_kernel<2><<<g2, blk, 0, stream>>>(nullptr, conf, nullptr, loc, dbox, out);
  }
}